// Round 1
// baseline (49483.463 us; speedup 1.0000x reference)
//
#include <hip/hip_runtime.h>

#define HIDDEN  100
#define GATES   400
#define SEQLEN  65536
#define XTILE   256
#define NTHREADS 512

__global__ __launch_bounds__(NTHREADS)
void lstm_seq_kernel(const float* __restrict__ x,      // [SEQ][4]
                     const float* __restrict__ W_ih,   // [400][4]
                     const float* __restrict__ W_hh,   // [400][100]
                     const float* __restrict__ b_ih,   // [400]
                     const float* __restrict__ b_hh,   // [400]
                     const float* __restrict__ W_lin,  // [1][100]
                     const float* __restrict__ b_lin,  // [1]
                     float* __restrict__ out)          // [1]
{
    __shared__ __align__(16) float  h_lds[112];   // hidden state (padded)
    __shared__ float  gact[GATES];                // activated gates i,f,g,o
    __shared__ __align__(16) float4 xs[XTILE];    // staged input tile
    __shared__ float  red[128];                   // final reduction

    const int tid = threadIdx.x;
    const bool is_gate = (tid < GATES);
    const bool is_cell = (tid < HIDDEN);

    // ---- load per-thread weights into registers (one-time) ----
    float4 wr[25];                 // W_hh row, 100 floats
    float4 wih = make_float4(0.f, 0.f, 0.f, 0.f);
    float  bias = 0.f;
    if (is_gate) {
        const float4* wrow = reinterpret_cast<const float4*>(W_hh + tid * HIDDEN);
#pragma unroll
        for (int q = 0; q < 25; ++q) wr[q] = wrow[q];
        wih  = reinterpret_cast<const float4*>(W_ih)[tid];
        bias = b_ih[tid] + b_hh[tid];
    }

    // ---- init state ----
    if (tid < 112) h_lds[tid] = 0.f;
    float c = 0.f;
    __syncthreads();

    for (int t0 = 0; t0 < SEQLEN; t0 += XTILE) {
        // stage next x tile (readers of previous tile finished before last barrier)
        if (tid < XTILE) xs[tid] = reinterpret_cast<const float4*>(x)[t0 + tid];
        __syncthreads();

        for (int tt = 0; tt < XTILE; ++tt) {
            if (is_gate) {
                // gate pre-activation: bias + W_ih·x_t + W_hh·h
                float4 xv = xs[tt];
                float4 acc;
                acc.x = __builtin_fmaf(wih.x, xv.x, bias);
                acc.y = wih.y * xv.y;
                acc.z = wih.z * xv.z;
                acc.w = wih.w * xv.w;
                const float4* hv = reinterpret_cast<const float4*>(h_lds);
#pragma unroll
                for (int q = 0; q < 25; ++q) {
                    float4 h4 = hv[q];            // broadcast LDS read
                    acc.x = __builtin_fmaf(wr[q].x, h4.x, acc.x);
                    acc.y = __builtin_fmaf(wr[q].y, h4.y, acc.y);
                    acc.z = __builtin_fmaf(wr[q].z, h4.z, acc.z);
                    acc.w = __builtin_fmaf(wr[q].w, h4.w, acc.w);
                }
                float s = (acc.x + acc.y) + (acc.z + acc.w);

                float act;
                if (tid < 2 * HIDDEN || tid >= 3 * HIDDEN) {
                    // sigmoid (gates i, f, o)
                    act = 1.0f / (1.0f + __expf(-s));
                } else {
                    // tanh (gate g)
                    float e = __expf(2.0f * s);
                    act = 1.0f - 2.0f / (e + 1.0f);
                }
                gact[tid] = act;
            }
            __syncthreads();

            if (is_cell) {
                float ig = gact[tid];
                float fg = gact[HIDDEN   + tid];
                float gg = gact[2*HIDDEN + tid];
                float og = gact[3*HIDDEN + tid];
                c = __builtin_fmaf(fg, c, ig * gg);
                float e  = __expf(2.0f * c);
                float th = 1.0f - 2.0f / (e + 1.0f);
                h_lds[tid] = og * th;
            }
            __syncthreads();
        }
    }

    // ---- final linear: out = h · W_lin^T + b_lin ----
    if (is_cell) red[tid] = h_lds[tid] * W_lin[tid];
    __syncthreads();
    if (tid == 0) {
        float s = b_lin[0];
        for (int j = 0; j < HIDDEN; ++j) s += red[j];
        out[0] = s;
    }
}

extern "C" void kernel_launch(void* const* d_in, const int* in_sizes, int n_in,
                              void* d_out, int out_size, void* d_ws, size_t ws_size,
                              hipStream_t stream) {
    const float* x     = (const float*)d_in[0];
    const float* W_ih  = (const float*)d_in[1];
    const float* W_hh  = (const float*)d_in[2];
    const float* b_ih  = (const float*)d_in[3];
    const float* b_hh  = (const float*)d_in[4];
    const float* W_lin = (const float*)d_in[5];
    const float* b_lin = (const float*)d_in[6];
    float* out = (float*)d_out;

    lstm_seq_kernel<<<dim3(1), dim3(NTHREADS), 0, stream>>>(
        x, W_ih, W_hh, b_ih, b_hh, W_lin, b_lin, out);
}

// Round 2
// 41058.694 us; speedup vs baseline: 1.2052x; 1.2052x over previous
//
#include <hip/hip_runtime.h>

#define HIDDEN  100
#define GATES   400
#define SEQLEN  65536
#define XTILE   256
#define NT      448   // 7 waves: 400 gate threads + x-staging helpers

// quad_perm DPP controls: lane <- lane^1 / ^2 / ^3 within each 4-lane group
#define DPP_XOR1 0xB1  // [1,0,3,2]
#define DPP_XOR2 0x4E  // [2,3,0,1]
#define DPP_XOR3 0x1B  // [3,2,1,0]

#if defined(__has_builtin) && __has_builtin(__builtin_amdgcn_rcpf)
#define RCPF(x) __builtin_amdgcn_rcpf(x)
#else
#define RCPF(x) (1.0f / (x))
#endif

#if defined(__has_builtin) && __has_builtin(__builtin_amdgcn_mov_dpp)
#define QSWAP(v, ctrl) __int_as_float(__builtin_amdgcn_mov_dpp(__float_as_int(v), (ctrl), 0xf, 0xf, true))
#else
#define QSWAP(v, ctrl) 0.0f  // unreachable fallback; gfx950 has mov_dpp
#endif

__global__ __launch_bounds__(NT, 2)
void lstm_seq2(const float* __restrict__ x,      // [SEQ][4]
               const float* __restrict__ W_ih,   // [400][4]
               const float* __restrict__ W_hh,   // [400][100]
               const float* __restrict__ b_ih,   // [400]
               const float* __restrict__ b_hh,   // [400]
               const float* __restrict__ W_lin,  // [1][100]
               const float* __restrict__ b_lin,  // [1]
               float* __restrict__ out)          // [1]
{
    __shared__ __align__(16) float  hbuf[2][112];  // double-buffered hidden state
    __shared__ __align__(16) float4 xs[XTILE];     // staged input tile
    __shared__ float red[112];

    const int tid = threadIdx.x;
    const int j   = tid >> 2;       // h index 0..99
    const int k   = tid & 3;        // gate type: 0=i 1=f 2=g 3=o
    const int r   = k * HIDDEN + j; // row in weight matrices
    const bool is_gate = (tid < GATES);

    // ---- per-thread weights in registers (no spill: launch_bounds allows 256 VGPR) ----
    float4 wr[25];                  // W_hh row (100 floats = 100 VGPRs)
    float4 wih = make_float4(0.f, 0.f, 0.f, 0.f);
    float bias = 0.f, m = 1.f, m1 = 0.f;
    if (is_gate) {
        const float4* wrow = reinterpret_cast<const float4*>(W_hh + r * HIDDEN);
#pragma unroll
        for (int q = 0; q < 25; ++q) wr[q] = wrow[q];
        wih  = reinterpret_cast<const float4*>(W_ih)[r];
        bias = b_ih[r] + b_hh[r];
        m  = (k == 2) ? 2.0f : 1.0f;  // tanh(s) = 2*sigmoid(2s)-1
        m1 = m - 1.0f;
    }
    float c = 0.f;                  // cell state lives in lanes with k==0

    if (tid < 112) { hbuf[0][tid] = 0.f; hbuf[1][tid] = 0.f; }
    __syncthreads();

    // one barrier per step: read hr, write hw (other buffer), sync
    auto step = [&](const float* hr, float* hw, const float4 xv) {
        if (is_gate) {
            const float4* h4 = reinterpret_cast<const float4*>(hr);
            float a0 = __builtin_fmaf(wih.x, xv.x, bias);
            float a1 = wih.y * xv.y;
            float a2 = wih.z * xv.z;
            float a3 = wih.w * xv.w;
#pragma unroll
            for (int q = 0; q < 25; ++q) {
                float4 h = h4[q];            // LDS broadcast read
                a0 = __builtin_fmaf(wr[q].x, h.x, a0);
                a1 = __builtin_fmaf(wr[q].y, h.y, a1);
                a2 = __builtin_fmaf(wr[q].z, h.z, a2);
                a3 = __builtin_fmaf(wr[q].w, h.w, a3);
            }
            float s = (a0 + a1) + (a2 + a3);
            // unified activation: sigmoid for i,f,o (m=1); tanh via 2*sig(2s)-1 (m=2)
            float u   = s * m;
            float e   = __expf(-u);
            float a   = RCPF(1.0f + e);
            float act = __builtin_fmaf(m, a, -m1);
            // gather the quad's 4 activations into lane k==0 (VALU DPP, no barrier)
            float g1 = QSWAP(act, DPP_XOR1);   // act of lane^1
            float g2 = QSWAP(act, DPP_XOR2);   // act of lane^2
            float g3 = QSWAP(g1,  DPP_XOR2);   // act of lane^3
            if (k == 0) {
                float ig = act, fg = g1, gg = g2, og = g3;
                c = __builtin_fmaf(fg, c, ig * gg);
                float e2 = __expf(2.0f * c);
                float th = __builtin_fmaf(-2.0f, RCPF(1.0f + e2), 1.0f); // tanh(c)
                hw[j] = og * th;
            }
        }
        __syncthreads();
    };

    const float4* x4 = reinterpret_cast<const float4*>(x);
    for (int t0 = 0; t0 < SEQLEN; t0 += XTILE) {
        if (tid < XTILE) xs[tid] = x4[t0 + tid];
        __syncthreads();
        for (int tt = 0; tt < XTILE; tt += 2) {
            step(hbuf[0], hbuf[1], xs[tt]);      // even step: read buf0, write buf1
            step(hbuf[1], hbuf[0], xs[tt + 1]);  // odd step: read buf1, write buf0
        }
    }
    // after an even number of steps the current h is in hbuf[0]

    if (tid < HIDDEN) red[tid] = hbuf[0][tid] * W_lin[tid];
    __syncthreads();
    if (tid == 0) {
        float s = b_lin[0];
        for (int q = 0; q < HIDDEN; ++q) s += red[q];
        out[0] = s;
    }
}

extern "C" void kernel_launch(void* const* d_in, const int* in_sizes, int n_in,
                              void* d_out, int out_size, void* d_ws, size_t ws_size,
                              hipStream_t stream) {
    const float* x     = (const float*)d_in[0];
    const float* W_ih  = (const float*)d_in[1];
    const float* W_hh  = (const float*)d_in[2];
    const float* b_ih  = (const float*)d_in[3];
    const float* b_hh  = (const float*)d_in[4];
    const float* W_lin = (const float*)d_in[5];
    const float* b_lin = (const float*)d_in[6];
    float* out = (float*)d_out;

    lstm_seq2<<<dim3(1), dim3(NT), 0, stream>>>(
        x, W_ih, W_hh, b_ih, b_hh, W_lin, b_lin, out);
}

// Round 3
// 35553.201 us; speedup vs baseline: 1.3918x; 1.1549x over previous
//
#include <hip/hip_runtime.h>

#define HIDDEN  100
#define GATES   400
#define SEQLEN  65536
#define XTILE   256
#define NT      448   // 7 waves: 400 gate threads + x-staging helpers

typedef float f32x2 __attribute__((ext_vector_type(2)));
typedef float f32x4 __attribute__((ext_vector_type(4)));

// quad_perm DPP controls: lane <- lane^1 / ^2 within each 4-lane group
#define DPP_XOR1 0xB1  // [1,0,3,2]
#define DPP_XOR2 0x4E  // [2,3,0,1]

#if defined(__has_builtin) && __has_builtin(__builtin_amdgcn_rcpf)
#define RCPF(x) __builtin_amdgcn_rcpf(x)
#else
#define RCPF(x) (1.0f / (x))
#endif

#define QSWAP(v, ctrl) __int_as_float(__builtin_amdgcn_mov_dpp(__float_as_int(v), (ctrl), 0xf, 0xf, true))

static __device__ __forceinline__ f32x2 pkfma(f32x2 a, f32x2 b, f32x2 c) {
#if defined(__has_builtin) && __has_builtin(__builtin_elementwise_fma)
    return __builtin_elementwise_fma(a, b, c);   // -> v_pk_fma_f32
#else
    f32x2 r; r.x = __builtin_fmaf(a.x, b.x, c.x); r.y = __builtin_fmaf(a.y, b.y, c.y); return r;
#endif
}

__global__ __launch_bounds__(NT) __attribute__((amdgpu_waves_per_eu(2, 2)))
void lstm_seq3(const float* __restrict__ x,      // [SEQ][4]
               const float* __restrict__ W_ih,   // [400][4]
               const float* __restrict__ W_hh,   // [400][100]
               const float* __restrict__ b_ih,   // [400]
               const float* __restrict__ b_hh,   // [400]
               const float* __restrict__ W_lin,  // [1][100]
               const float* __restrict__ b_lin,  // [1]
               float* __restrict__ out)          // [1]
{
    __shared__ __align__(16) float  hbuf[2][112];  // double-buffered hidden state
    __shared__ __align__(16) f32x4  xs[XTILE];     // staged input tile
    __shared__ float red[112];

    const int tid = threadIdx.x;
    const int j   = tid >> 2;       // h index 0..99
    const int k   = tid & 3;        // gate type: 0=i 1=f 2=g 3=o
    const int r   = k * HIDDEN + j; // row in weight matrices
    const bool is_gate = (tid < GATES);

    // ---- per-thread W_hh row in registers (amdgpu_waves_per_eu(2,2) => 256 VGPR budget) ----
    f32x4 wr[25];                   // 100 floats
    f32x4 wih = (f32x4)(0.f);
    float bias = 0.f, m = 1.f, m1 = 0.f;
    if (is_gate) {
        const f32x4* wrow = reinterpret_cast<const f32x4*>(W_hh + r * HIDDEN);
#pragma unroll
        for (int q = 0; q < 25; ++q) wr[q] = wrow[q];
        wih  = reinterpret_cast<const f32x4*>(W_ih)[r];
        bias = b_ih[r] + b_hh[r];
        m  = (k == 2) ? 2.0f : 1.0f;  // tanh(s) = 2*sigmoid(2s)-1
        m1 = m - 1.0f;
    }
    float c = 0.f;                  // cell state lives in k==0 lanes

    if (tid < 112) { hbuf[0][tid] = 0.f; hbuf[1][tid] = 0.f; }
    __syncthreads();

    // one barrier per step: read hr, write hw (other buffer), sync
    auto step = [&](const float* hr, float* hw, const f32x4 xv) {
        if (is_gate) {
            const f32x4* h4 = reinterpret_cast<const f32x4*>(hr);
            // 4 packed accumulator chains
            f32x2 acc0, acc1, acc2, acc3;
            acc0.x = __builtin_fmaf(wih.x, xv.x, bias);
            acc0.y = wih.y * xv.y;
            acc1.x = wih.z * xv.z;
            acc1.y = wih.w * xv.w;
            acc2 = (f32x2)(0.f);
            acc3 = (f32x2)(0.f);
#pragma unroll
            for (int q = 0; q < 25; ++q) {
                f32x4 h = h4[q];               // LDS broadcast read
                if (q & 1) {
                    acc2 = pkfma(wr[q].xy, h.xy, acc2);
                    acc3 = pkfma(wr[q].zw, h.zw, acc3);
                } else {
                    acc0 = pkfma(wr[q].xy, h.xy, acc0);
                    acc1 = pkfma(wr[q].zw, h.zw, acc1);
                }
            }
            f32x2 sv = (acc0 + acc1) + (acc2 + acc3);  // v_pk_add_f32
            float s  = sv.x + sv.y;
            // unified activation: sigmoid for i,f,o (m=1); tanh via 2*sig(2s)-1 (m=2)
            float u   = s * m;
            float e   = __expf(-u);
            float a   = RCPF(1.0f + e);
            float act = __builtin_fmaf(m, a, -m1);
            // gather the quad's 4 activations into lane k==0 (VALU DPP, no barrier)
            float g1 = QSWAP(act, DPP_XOR1);   // act of lane^1
            float g2 = QSWAP(act, DPP_XOR2);   // act of lane^2
            float g3 = QSWAP(g1,  DPP_XOR2);   // act of lane^3
            if (k == 0) {
                float ig = act, fg = g1, gg = g2, og = g3;
                c = __builtin_fmaf(fg, c, ig * gg);
                float e2 = __expf(2.0f * c);
                float th = __builtin_fmaf(-2.0f, RCPF(1.0f + e2), 1.0f); // tanh(c)
                hw[j] = og * th;
            }
        }
        __syncthreads();
    };

    const f32x4* x4 = reinterpret_cast<const f32x4*>(x);
    for (int t0 = 0; t0 < SEQLEN; t0 += XTILE) {
        if (tid < XTILE) xs[tid] = x4[t0 + tid];
        __syncthreads();
        for (int tt = 0; tt < XTILE; tt += 2) {
            step(hbuf[0], hbuf[1], xs[tt]);      // even: read buf0, write buf1
            step(hbuf[1], hbuf[0], xs[tt + 1]);  // odd:  read buf1, write buf0
        }
    }
    // after an even number of steps the current h is in hbuf[0]

    if (tid < HIDDEN) red[tid] = hbuf[0][tid] * W_lin[tid];
    __syncthreads();
    if (tid == 0) {
        float s = b_lin[0];
        for (int q = 0; q < HIDDEN; ++q) s += red[q];
        out[0] = s;
    }
}

extern "C" void kernel_launch(void* const* d_in, const int* in_sizes, int n_in,
                              void* d_out, int out_size, void* d_ws, size_t ws_size,
                              hipStream_t stream) {
    const float* x     = (const float*)d_in[0];
    const float* W_ih  = (const float*)d_in[1];
    const float* W_hh  = (const float*)d_in[2];
    const float* b_ih  = (const float*)d_in[3];
    const float* b_hh  = (const float*)d_in[4];
    const float* W_lin = (const float*)d_in[5];
    const float* b_lin = (const float*)d_in[6];
    float* out = (float*)d_out;

    lstm_seq3<<<dim3(1), dim3(NT), 0, stream>>>(
        x, W_ih, W_hh, b_ih, b_hh, W_lin, b_lin, out);
}